// Round 5
// baseline (237.956 us; speedup 1.0000x reference)
//
#include <hip/hip_runtime.h>

// ---------------------------------------------------------------------------
// Channel attention (XCA): B=4, N=4096, C=768, H=8, HD=96, fp32 in/out.
// R9: gemm_bt = 256x256 / BK=64 / 8 waves (2x4, per-wave 128x64) / 2-deep
// LDS dbuf (128KB) / 8-phase schedule. FIX vs R8: staging halves re-mapped
// to match READ halves (A-h = mh blocks: row16=(w>>2)*8+h*4+(w&3);
// B-h = nh blocks: row16=(w>>1)*4+h*2+(w&1)), so each region's lifetime is
// per-phase. Stages: P1:A1(t1) P2:A0(t+2) P3:B0(t+2) P4:B1(t+2) P5:A1(t+2)
// P6:A0(t+3) P7:B0(t+3) P8:B1(t+3). Write-after-read: every region staged
// >=1 phase after last ds_read. Read-after-write: VM(10) (5 slots out) at
// ends of P1,P2,P4,P5,P6,P8 - forced loads are >=5 phases (~1000cy) old.
// Prologue order A0(0),B0(0),B1(0),A1(0),A0(1),B0(1),B1(1)+VM(10) makes
// iter0 = steady state. Last iter peels VM(8)/(4)/(2)/(0).
// ---------------------------------------------------------------------------

using bf16x8 = __attribute__((ext_vector_type(8))) short;
using f32x4  = __attribute__((ext_vector_type(4))) float;

#define SCALE_ 0.10206207261596575f   // 96^-0.5
#define KD 768

__device__ __forceinline__ unsigned short f2bf(float f) {
    unsigned int u = __builtin_bit_cast(unsigned int, f);
    u += 0x7FFFu + ((u >> 16) & 1u);          // RNE, finite inputs only
    return (unsigned short)(u >> 16);
}
__device__ __forceinline__ float bf2f(unsigned short h) {
    unsigned int u = ((unsigned int)h) << 16;
    return __builtin_bit_cast(float, u);
}

__device__ __forceinline__ void glds16(const unsigned short* g, unsigned short* l) {
    __builtin_amdgcn_global_load_lds(
        (const __attribute__((address_space(1))) void*)g,
        (__attribute__((address_space(3))) void*)l, 16, 0, 0);
}

// sum of squares of 8 bf16 packed in a frag
__device__ __forceinline__ float ssq8(bf16x8 v) {
    uint4 u = __builtin_bit_cast(uint4, v);
    unsigned a[4] = {u.x, u.y, u.z, u.w};
    float s = 0.f;
    #pragma unroll
    for (int i = 0; i < 4; i++) {
        float lo = __builtin_bit_cast(float, a[i] << 16);
        float hi = __builtin_bit_cast(float, a[i] & 0xFFFF0000u);
        s += lo * lo + hi * hi;
    }
    return s;
}

// ---------------------------------------------------------------------------
// fp32 -> bf16 bulk convert (memory-bound). 8 elems/thread.
// ---------------------------------------------------------------------------
__global__ void f32_to_bf16_k(const float* __restrict__ in,
                              unsigned short* __restrict__ out)
{
    size_t idx = ((size_t)blockIdx.x * 256 + threadIdx.x) * 8;
    float4 v0 = *(const float4*)&in[idx];
    float4 v1 = *(const float4*)&in[idx + 4];
    unsigned short h[8];
    h[0] = f2bf(v0.x); h[1] = f2bf(v0.y); h[2] = f2bf(v0.z); h[3] = f2bf(v0.w);
    h[4] = f2bf(v1.x); h[5] = f2bf(v1.y); h[6] = f2bf(v1.z); h[7] = f2bf(v1.w);
    *(bf16x8*)&out[idx] = *(bf16x8*)h;
}

// ---------------------------------------------------------------------------
// Weight transpose + fp32->bf16: W[K][N] -> Wt[N][K]. block(32,8).
// ---------------------------------------------------------------------------
__global__ void transpose_to_bf16(const float* __restrict__ W,
                                  unsigned short* __restrict__ Wt,
                                  int K, int N)
{
    __shared__ float tile[32][33];
    int n0 = blockIdx.x * 32, k0 = blockIdx.y * 32;
    int tx = threadIdx.x, ty = threadIdx.y;
    #pragma unroll
    for (int i = 0; i < 32; i += 8)
        tile[ty + i][tx] = W[(size_t)(k0 + ty + i) * N + n0 + tx];
    __syncthreads();
    #pragma unroll
    for (int i = 0; i < 32; i += 8)
        Wt[(size_t)(n0 + ty + i) * K + k0 + tx] = f2bf(tile[tx][ty + i]);
}

// ---------------------------------------------------------------------------
// GEMM: C = A[M][768] * Bt[N][768]^T, bf16. 256x256 block, BK=64, 8 waves
// 2x4, per-wave 128x64 (8x4 frags of 16x16x32 MFMA). Fragment-order 1KB LDS
// blocks: block = kc*16 + row16 holds rows row16*16+(lane&15),
// k = kc*32+(lane>>4)*8 at lane*16B -> glds16 staging and ds_read_b128
// fragment reads both lane-sequential (0 bank conflicts).
// MODE 0: write transposed bf16 Qt[bh][d][n]     (out0)
// MODE 1: cols<768 -> Kt[bh][d][n] (out0); cols>=768 -> Vb[m][768] (out1)
// MODE 2: fp32 + bias row-major (out0)
// ---------------------------------------------------------------------------

#define BAR __builtin_amdgcn_s_barrier()
#define VM(n) asm volatile("s_waitcnt vmcnt(" #n ")" ::: "memory")

// A-half h covers exactly the blocks RD_A(*,h) reads: row16=(w>>2)*8+h*4+(w&3)
#define ST_A(buf, tt, h) do { \
    const int r16a_ = (w >> 2) * 8 + (h) * 4 + (w & 3); \
    _Pragma("unroll") \
    for (int c_ = 0; c_ < 2; c_++) \
        glds16(gA + (size_t)(r16a_ * 16) * KD + (tt) * 64 + c_ * 32, \
               &As[buf][(c_ * 16 + r16a_) * 512]); \
} while (0)

// B-half h covers exactly the blocks RD_B(*,h) reads: row16=(w>>1)*4+h*2+(w&1)
#define ST_B(buf, tt, h) do { \
    const int r16b_ = (w >> 1) * 4 + (h) * 2 + (w & 1); \
    _Pragma("unroll") \
    for (int c_ = 0; c_ < 2; c_++) \
        glds16(gB + (size_t)(r16b_ * 16) * KD + (tt) * 64 + c_ * 32, \
               &Bs[buf][(c_ * 16 + r16b_) * 512]); \
} while (0)

#define RD_A(buf, mh) do { \
    _Pragma("unroll") \
    for (int i_ = 0; i_ < 4; i_++) \
    _Pragma("unroll") \
    for (int kk_ = 0; kk_ < 2; kk_++) \
        a[i_][kk_] = *(const bf16x8*)&As[buf][(kk_ * 16 + wr * 8 + (mh) * 4 + i_) * 512 + lane * 8]; \
} while (0)

#define RD_B(buf, nh) do { \
    _Pragma("unroll") \
    for (int j_ = 0; j_ < 2; j_++) \
    _Pragma("unroll") \
    for (int kk_ = 0; kk_ < 2; kk_++) \
        b[nh][j_][kk_] = *(const bf16x8*)&Bs[buf][(kk_ * 16 + wc * 4 + (nh) * 2 + j_) * 512 + lane * 8]; \
} while (0)

#define MM(mh, nh) do { \
    __builtin_amdgcn_s_setprio(1); \
    _Pragma("unroll") \
    for (int i_ = 0; i_ < 4; i_++) \
    _Pragma("unroll") \
    for (int j_ = 0; j_ < 2; j_++) \
    _Pragma("unroll") \
    for (int kk_ = 0; kk_ < 2; kk_++) \
        acc[(mh) * 4 + i_][(nh) * 2 + j_] = __builtin_amdgcn_mfma_f32_16x16x32_bf16( \
            a[i_][kk_], b[nh][j_][kk_], acc[(mh) * 4 + i_][(nh) * 2 + j_], 0, 0, 0); \
    __builtin_amdgcn_s_setprio(0); \
} while (0)

// one iteration = K-tiles t0 (buf0) and t0+1 (buf1), 8 phases.
// Waits (non-last): VM(10) at ends of P1,P2,P4,P5,P6,P8 (5 slots out,
// forced load >=5 phases old). Last iter: VM(10)/(8)/-/(4)/(2)/(0)/-/-.
#define KITER(t0v, LAST) do { \
    /* P1 */ RD_A(0, 0); RD_B(0, 0); ST_A(1, (t0v) + 1, 1); \
             BAR; MM(0, 0); VM(10); BAR; \
    /* P2 */ RD_B(0, 1); if (!(LAST)) ST_A(0, (t0v) + 2, 0); \
             BAR; MM(0, 1); if (LAST) { VM(8); } else { VM(10); } BAR; \
    /* P3 */ RD_A(0, 1); if (!(LAST)) ST_B(0, (t0v) + 2, 0); \
             BAR; MM(1, 0); BAR; \
    /* P4 */ if (!(LAST)) ST_B(0, (t0v) + 2, 1); \
             BAR; MM(1, 1); if (LAST) { VM(4); } else { VM(10); } BAR; \
    /* P5 */ RD_A(1, 0); RD_B(1, 0); if (!(LAST)) ST_A(0, (t0v) + 2, 1); \
             BAR; MM(0, 0); if (LAST) { VM(2); } else { VM(10); } BAR; \
    /* P6 */ RD_B(1, 1); if (!(LAST)) ST_A(1, (t0v) + 3, 0); \
             BAR; MM(0, 1); if (LAST) { VM(0); } else { VM(10); } BAR; \
    /* P7 */ RD_A(1, 1); if (!(LAST)) ST_B(1, (t0v) + 3, 0); \
             BAR; MM(1, 0); BAR; \
    /* P8 */ if (!(LAST)) { ST_B(1, (t0v) + 3, 1); } \
             BAR; MM(1, 1); if (!(LAST)) { VM(10); } BAR; \
} while (0)

template<int MODE>
__global__ __launch_bounds__(512, 2) void gemm_bt(
    const unsigned short* __restrict__ A, const unsigned short* __restrict__ Bt,
    const float* __restrict__ bias, void* __restrict__ out0, void* __restrict__ out1,
    int M, int N)
{
    __shared__ unsigned short As[2][32 * 512];   // 2 x 32KB
    __shared__ unsigned short Bs[2][32 * 512];

    const int Nt = gridDim.x, Mt = gridDim.y;
    const int lin = blockIdx.y * Nt + blockIdx.x;
    const int xcd = lin & 7, li = lin >> 3;
    const int band = Mt >> 3;
    const int mt = xcd * band + (li % band);
    const int nt = li / band;
    const int bm = mt * 256, bn = nt * 256;

    const int t = threadIdx.x, lane = t & 63, w = t >> 6;
    const int wr = w >> 2, wc = w & 3;            // 2 x 4 wave grid
    const int mf = lane & 15, quad = lane >> 4;

    const unsigned short* gA = A  + (size_t)(bm + (lane & 15)) * KD + (lane >> 4) * 8;
    const unsigned short* gB = Bt + (size_t)(bn + (lane & 15)) * KD + (lane >> 4) * 8;

    f32x4 acc[8][4] = {};
    bf16x8 a[4][2], b[2][2][2];

    // prologue: order A0(0),B0(0),B1(0),A1(0),A0(1),B0(1),B1(1) = 7 slots;
    // VM(10) leaves 5 newest outstanding -> A0(0),B0(0) complete for P1.
    ST_A(0, 0, 0); ST_B(0, 0, 0); ST_B(0, 0, 1); ST_A(0, 0, 1);
    ST_A(1, 1, 0); ST_B(1, 1, 0); ST_B(1, 1, 1);
    VM(10);
    BAR;

    // 12 K-tiles = 6 iterations
    #pragma unroll 1
    for (int it = 0; it < 5; ++it) { KITER(2 * it, false); }
    KITER(10, true);

    // C/D layout: col = lane&15, row = quad*4 + r
    if constexpr (MODE == 2) {
        float* C = (float*)out0;
        #pragma unroll
        for (int i = 0; i < 8; i++) {
            int row0 = bm + wr * 128 + i * 16 + quad * 4;
            #pragma unroll
            for (int j = 0; j < 4; j++) {
                int col = bn + wc * 64 + j * 16 + mf;
                float bv = bias[col];
                #pragma unroll
                for (int r = 0; r < 4; r++)
                    C[(size_t)(row0 + r) * N + col] = acc[i][j][r] + bv;
            }
        }
    } else {
        unsigned short* Tr = (unsigned short*)out0;   // Qt or Kt [bh][96][4096]
        unsigned short* Vb = (unsigned short*)out1;   // [16384][768]
        const bool kpart = (MODE == 0) || (bn < 768); // uniform (bn mult of 256)
        #pragma unroll
        for (int i = 0; i < 8; i++) {
            int row0 = bm + wr * 128 + i * 16 + quad * 4;  // global token index
            int bb = row0 >> 12, n = row0 & 4095;
            #pragma unroll
            for (int j = 0; j < 4; j++) {
                int c = bn + wc * 64 + j * 16 + mf;
                if (kpart) {
                    int h = (c * 683) >> 16;          // floor(c/96) for c<768
                    int d = c - h * 96;
                    size_t o = ((size_t)((bb * 8 + h) * 96 + d)) * 4096 + n;
                    ushort4 v4;
                    v4.x = f2bf(acc[i][j][0]); v4.y = f2bf(acc[i][j][1]);
                    v4.z = f2bf(acc[i][j][2]); v4.w = f2bf(acc[i][j][3]);
                    *(ushort4*)&Tr[o] = v4;
                } else {
                    int cv = c - 768;
                    #pragma unroll
                    for (int r = 0; r < 4; r++)
                        Vb[(size_t)(row0 + r) * 768 + cv] = f2bf(acc[i][j][r]);
                }
            }
        }
    }
}

#undef KITER
#undef MM
#undef RD_A
#undef RD_B
#undef ST_A
#undef ST_B
#undef VM
#undef BAR

// ---------------------------------------------------------------------------
// S-gram: Spart[bh][s][96][96] = sum over 512-n window of Qt[d][n]*Kt[e][n].
// ---------------------------------------------------------------------------
__global__ __launch_bounds__(256) void s_gemm(
    const unsigned short* __restrict__ Qt, const unsigned short* __restrict__ Kt,
    float* __restrict__ Spart, float* __restrict__ ssq)
{
    __shared__ unsigned short Qs[2][12 * 512];
    __shared__ unsigned short Ks[2][12 * 512];
    const int s = blockIdx.x, bh = blockIdx.y;
    const int t = threadIdx.x, lane = t & 63, w = t >> 6;
    const int m0 = (w >> 1) * 48, n0w = (w & 1) * 48;
    const int mf = lane & 15, quad = lane >> 4;
    const int srow = lane & 15, skc = (lane >> 4) * 8;
    const int nwin = s * 512;

    const unsigned short* Qg = Qt + (size_t)bh * 96 * 4096;
    const unsigned short* Kg = Kt + (size_t)bh * 96 * 4096;

    f32x4 acc[3][3] = {};
    float sq[3] = {0.f, 0.f, 0.f}, sk[3] = {0.f, 0.f, 0.f};

    #pragma unroll
    for (int c = 0; c < 3; c++) {
        int bi = w * 3 + c, kc = bi / 6, g = bi % 6;
        size_t go = (size_t)(g * 16 + srow) * 4096 + nwin + kc * 32 + skc;
        glds16(Qg + go, &Qs[0][bi * 512]);
        glds16(Kg + go, &Ks[0][bi * 512]);
    }

    for (int it = 0; it < 8; it++) {
        const int cur = it & 1;
        __syncthreads();
        if (it + 1 < 8) {
            const int nxt = cur ^ 1;
            const int nn = nwin + (it + 1) * 64;
            #pragma unroll
            for (int c = 0; c < 3; c++) {
                int bi = w * 3 + c, kc = bi / 6, g = bi % 6;
                size_t go = (size_t)(g * 16 + srow) * 4096 + nn + kc * 32 + skc;
                glds16(Qg + go, &Qs[nxt][bi * 512]);
                glds16(Kg + go, &Ks[nxt][bi * 512]);
            }
        }
        #pragma unroll
        for (int kk = 0; kk < 2; kk++) {
            bf16x8 a[3], b[3];
            #pragma unroll
            for (int i = 0; i < 3; i++)
                a[i] = *(const bf16x8*)&Qs[cur][(kk * 6 + (w >> 1) * 3 + i) * 512 + lane * 8];
            #pragma unroll
            for (int j = 0; j < 3; j++)
                b[j] = *(const bf16x8*)&Ks[cur][(kk * 6 + (w & 1) * 3 + j) * 512 + lane * 8];
            if ((w & 1) == 0) {
                #pragma unroll
                for (int i = 0; i < 3; i++) sq[i] += ssq8(a[i]);
            }
            if ((w >> 1) == 0) {
                #pragma unroll
                for (int j = 0; j < 3; j++) sk[j] += ssq8(b[j]);
            }
            #pragma unroll
            for (int i = 0; i < 3; i++)
                #pragma unroll
                for (int j = 0; j < 3; j++)
                    acc[i][j] = __builtin_amdgcn_mfma_f32_16x16x32_bf16(a[i], b[j], acc[i][j], 0, 0, 0);
        }
    }

    if ((w & 1) == 0) {
        #pragma unroll
        for (int i = 0; i < 3; i++) {
            float v = sq[i];
            v += __shfl_xor(v, 16, 64);
            v += __shfl_xor(v, 32, 64);
            if (lane < 16) atomicAdd(&ssq[bh * 96 + m0 + i * 16 + lane], v);
        }
    }
    if ((w >> 1) == 0) {
        #pragma unroll
        for (int j = 0; j < 3; j++) {
            float v = sk[j];
            v += __shfl_xor(v, 16, 64);
            v += __shfl_xor(v, 32, 64);
            if (lane < 16) atomicAdd(&ssq[3072 + bh * 96 + n0w + j * 16 + lane], v);
        }
    }

    float* outp = Spart + (size_t)(bh * 8 + s) * 9216;
    #pragma unroll
    for (int i = 0; i < 3; i++)
        #pragma unroll
        for (int j = 0; j < 3; j++) {
            int e  = n0w + j * 16 + mf;
            int d0 = m0 + i * 16 + quad * 4;
            #pragma unroll
            for (int r = 0; r < 4; r++)
                outp[(d0 + r) * 96 + e] = acc[i][j][r];
        }
}

// ---------------------------------------------------------------------------
// Softmax, wave-per-row: grid(24, 32bh) x 256 thr.
// ---------------------------------------------------------------------------
__global__ __launch_bounds__(256) void softmax_k(
    const float* __restrict__ Spart, const float* __restrict__ ssq,
    unsigned short* __restrict__ P)
{
    const int bh = blockIdx.y;
    const int d  = blockIdx.x * 4 + (threadIdx.x >> 6);
    const int lane = threadIdx.x & 63;

    const float sr = SCALE_ / fmaxf(sqrtf(ssq[bh * 96 + d]), 1e-12f);

    const float* Sp = Spart + (size_t)bh * 8 * 9216 + d * 96;
    float sa = 0.f, sb = 0.f;
    #pragma unroll
    for (int ch = 0; ch < 8; ch++) {
        sa += Sp[ch * 9216 + lane];
        if (lane < 32) sb += Sp[ch * 9216 + 64 + lane];
    }
    float ka = 1.0f / fmaxf(sqrtf(ssq[3072 + bh * 96 + lane]), 1e-12f);
    float va = sa * sr * ka;
    float vb = -1e30f;
    if (lane < 32) {
        float kb = 1.0f / fmaxf(sqrtf(ssq[3072 + bh * 96 + 64 + lane]), 1e-12f);
        vb = sb * sr * kb;
    }

    float m = fmaxf(va, vb);
    #pragma unroll
    for (int off = 32; off >= 1; off >>= 1)
        m = fmaxf(m, __shfl_xor(m, off, 64));

    float ea = __expf(va - m);
    float eb = (lane < 32) ? __expf(vb - m) : 0.f;
    float ssum = ea + eb;
    #pragma unroll
    for (int off = 32; off >= 1; off >>= 1)
        ssum += __shfl_xor(ssum, off, 64);

    float inv = 1.0f / ssum;
    unsigned short* Pr = P + (size_t)bh * 9216 + d * 96;
    Pr[lane] = f2bf(ea * inv);
    if (lane < 32) Pr[64 + lane] = f2bf(eb * inv);
}

// ---------------------------------------------------------------------------
// x[n][d] = sum_e V[n][e] * P[d][e] per (b,h). V from compact Vb[m][768].
// ---------------------------------------------------------------------------
__global__ __launch_bounds__(256) void pv_gemm(
    const unsigned short* __restrict__ Vb, const unsigned short* __restrict__ P,
    unsigned short* __restrict__ X)
{
    __shared__ unsigned short Ps[96][104];
    int ntile = blockIdx.x, bh = blockIdx.y;
    int b = bh >> 3, h = bh & 7;
    int t = threadIdx.x, lane = t & 63, w = t >> 6;

    const unsigned short* Pg = P + (size_t)bh * 9216;
    #pragma unroll
    for (int i = 0; i < 9; i++) {
        int idx4 = t + 256 * i;
        int row = idx4 / 24, c4 = (idx4 - row * 24) * 4;
        *(ushort4*)&Ps[row][c4] = *(const ushort4*)&Pg[row * 96 + c4];
    }
    __syncthreads();

    const unsigned short* Vbase = Vb + (size_t)b * 4096 * 768 + h * 96;
    int mf = lane & 15, k8 = (lane >> 4) * 8;
    f32x4 acc[2][6] = {};
    #pragma unroll
    for (int k = 0; k < 3; k++) {
        bf16x8 a[2], bb[6];
        #pragma unroll
        for (int i = 0; i < 2; i++) {
            int row = ntile * 128 + w * 32 + i * 16 + mf;
            a[i] = *(const bf16x8*)&Vbase[(size_t)row * 768 + k * 32 + k8];
        }
        #pragma unroll
        for (int j = 0; j < 6; j++)
            bb[j] = *(const bf16x8*)&Ps[j * 16 + mf][k * 32 + k8];
        #pragma unroll
        for (int i = 0; i < 2; i++)
            #pragma unroll
            for (int j = 0; j < 6; j++)
                acc[i][j] = __builtin_amdgcn_mfma_f32_16x16x32_bf16(a[i], bb[j], acc[i][j], 0, 0, 0);
    }
    #pragma unroll
    for (int i = 0; i < 2; i++)
        #pragma unroll
        for (int j = 0; j < 6; j++)
            #pragma unroll
            for (int r = 0; r < 4; r++) {
                int n_tok = ntile * 128 + w * 32 + i * 16 + (lane >> 4) * 4 + r;
                int c = h * 96 + j * 16 + mf;
                X[((size_t)b * 4096 + n_tok) * 768 + c] = f2bf(acc[i][j][r]);
            }
}

// ---------------------------------------------------------------------------
extern "C" void kernel_launch(void* const* d_in, const int* in_sizes, int n_in,
                              void* d_out, int out_size, void* d_ws, size_t ws_size,
                              hipStream_t stream)
{
    (void)in_sizes; (void)n_in; (void)out_size; (void)ws_size;
    const float* ctx   = (const float*)d_in[0];
    const float* dep   = (const float*)d_in[1];
    const float* Wq    = (const float*)d_in[2];
    const float* Wkv   = (const float*)d_in[3];
    const float* Wproj = (const float*)d_in[4];
    const float* bproj = (const float*)d_in[5];
    float* out = (float*)d_out;

    char* p = (char*)d_ws;
    auto carve = [&](size_t bytes) {
        char* r = p;
        p += (bytes + 255) & ~(size_t)255;
        return r;
    };
    unsigned short* WqT    = (unsigned short*)carve((size_t)768 * 768 * 2);
    unsigned short* WkvT   = (unsigned short*)carve((size_t)1536 * 768 * 2);
    unsigned short* WprojT = (unsigned short*)carve((size_t)768 * 768 * 2);
    unsigned short* Qt     = (unsigned short*)carve((size_t)32 * 96 * 4096 * 2);
    unsigned short* Kt     = (unsigned short*)carve((size_t)32 * 96 * 4096 * 2);
    unsigned short* Vb     = (unsigned short*)carve((size_t)16384 * 768 * 2);
    unsigned short* Xb     = (unsigned short*)carve((size_t)16384 * 768 * 2);
    float*          ssq    = (float*)carve((size_t)2 * 3072 * 4);
    float*          Spart  = (float*)carve((size_t)32 * 8 * 9216 * 4);
    unsigned short* Pb     = (unsigned short*)carve((size_t)32 * 9216 * 2);
    unsigned short* depB   = (unsigned short*)carve((size_t)16384 * 768 * 2);
    // ctx-bf16 aliases Xb: Q-gemm consumes it before pv_gemm writes Xb.
    unsigned short* ctxB   = Xb;

    hipMemsetAsync(ssq, 0, 2 * 3072 * 4, stream);

    f32_to_bf16_k<<<6144, 256, 0, stream>>>(ctx, ctxB);
    f32_to_bf16_k<<<6144, 256, 0, stream>>>(dep, depB);

    dim3 tb(32, 8);
    transpose_to_bf16<<<dim3(24, 24), tb, 0, stream>>>(Wq, WqT, 768, 768);
    transpose_to_bf16<<<dim3(48, 24), tb, 0, stream>>>(Wkv, WkvT, 768, 1536);
    transpose_to_bf16<<<dim3(24, 24), tb, 0, stream>>>(Wproj, WprojT, 768, 768);

    gemm_bt<0><<<dim3(3, 64), 512, 0, stream>>>(ctxB, WqT, nullptr, Qt, nullptr, 16384, 768);
    gemm_bt<1><<<dim3(6, 64), 512, 0, stream>>>(depB, WkvT, nullptr, Kt, Vb, 16384, 1536);

    s_gemm<<<dim3(8, 32), 256, 0, stream>>>(Qt, Kt, Spart, ssq);
    softmax_k<<<dim3(24, 32), 256, 0, stream>>>(Spart, ssq, Pb);
    pv_gemm<<<dim3(32, 32), 256, 0, stream>>>(Vb, Pb, Xb);
    gemm_bt<2><<<dim3(3, 64), 512, 0, stream>>>(Xb, WprojT, bproj, out, nullptr, 16384, 768);
}

// Round 6
// 229.556 us; speedup vs baseline: 1.0366x; 1.0366x over previous
//
#include <hip/hip_runtime.h>

// ---------------------------------------------------------------------------
// Channel attention (XCA): B=4, N=4096, C=768, H=8, HD=96, fp32 in/out.
// R10: gemm_bt retiled 128x384 / BK=64 / 8 waves (2x4, per-wave 64x96) so
// ALL grids pack 100%: MODE1 4x128=512 blocks (2 full rounds), MODE0/2
// 2x128=256 (1 full round). R9's HW-verified 8-phase schedule skeleton,
// waits re-counted for slot sizes (A-slot=1 load/wave, B-slot=3):
//  stages P1:A1(t1) P2:A0(t+2) P3:B0(t+2) P4:B1(t+2) P5:A1(t+2) P6:A0(t+3)
//  P7:B0(t+3) P8:B1(t+3); waits VM(9)@P1,P2,P5,P6, VM(11)@P4,P8.
// Every forced load >=5 phases old; every region staged >=1 barrier after
// its last reader. Prologue 15 loads + VM(11) => iter0 == steady state.
// Last iter peels VM(9)/(8)/-/(4)/(1)/(0)/-/-.
// ---------------------------------------------------------------------------

using bf16x8 = __attribute__((ext_vector_type(8))) short;
using f32x4  = __attribute__((ext_vector_type(4))) float;

#define SCALE_ 0.10206207261596575f   // 96^-0.5
#define KD 768

__device__ __forceinline__ unsigned short f2bf(float f) {
    unsigned int u = __builtin_bit_cast(unsigned int, f);
    u += 0x7FFFu + ((u >> 16) & 1u);          // RNE, finite inputs only
    return (unsigned short)(u >> 16);
}
__device__ __forceinline__ float bf2f(unsigned short h) {
    unsigned int u = ((unsigned int)h) << 16;
    return __builtin_bit_cast(float, u);
}

__device__ __forceinline__ void glds16(const unsigned short* g, unsigned short* l) {
    __builtin_amdgcn_global_load_lds(
        (const __attribute__((address_space(1))) void*)g,
        (__attribute__((address_space(3))) void*)l, 16, 0, 0);
}

// sum of squares of 8 bf16 packed in a frag
__device__ __forceinline__ float ssq8(bf16x8 v) {
    uint4 u = __builtin_bit_cast(uint4, v);
    unsigned a[4] = {u.x, u.y, u.z, u.w};
    float s = 0.f;
    #pragma unroll
    for (int i = 0; i < 4; i++) {
        float lo = __builtin_bit_cast(float, a[i] << 16);
        float hi = __builtin_bit_cast(float, a[i] & 0xFFFF0000u);
        s += lo * lo + hi * hi;
    }
    return s;
}

// ---------------------------------------------------------------------------
// fp32 -> bf16 bulk convert (memory-bound). 8 elems/thread.
// ---------------------------------------------------------------------------
__global__ void f32_to_bf16_k(const float* __restrict__ in,
                              unsigned short* __restrict__ out)
{
    size_t idx = ((size_t)blockIdx.x * 256 + threadIdx.x) * 8;
    float4 v0 = *(const float4*)&in[idx];
    float4 v1 = *(const float4*)&in[idx + 4];
    unsigned short h[8];
    h[0] = f2bf(v0.x); h[1] = f2bf(v0.y); h[2] = f2bf(v0.z); h[3] = f2bf(v0.w);
    h[4] = f2bf(v1.x); h[5] = f2bf(v1.y); h[6] = f2bf(v1.z); h[7] = f2bf(v1.w);
    *(bf16x8*)&out[idx] = *(bf16x8*)h;
}

// ---------------------------------------------------------------------------
// Weight transpose + fp32->bf16: W[K][N] -> Wt[N][K]. block(32,8).
// ---------------------------------------------------------------------------
__global__ void transpose_to_bf16(const float* __restrict__ W,
                                  unsigned short* __restrict__ Wt,
                                  int K, int N)
{
    __shared__ float tile[32][33];
    int n0 = blockIdx.x * 32, k0 = blockIdx.y * 32;
    int tx = threadIdx.x, ty = threadIdx.y;
    #pragma unroll
    for (int i = 0; i < 32; i += 8)
        tile[ty + i][tx] = W[(size_t)(k0 + ty + i) * N + n0 + tx];
    __syncthreads();
    #pragma unroll
    for (int i = 0; i < 32; i += 8)
        Wt[(size_t)(n0 + ty + i) * K + k0 + tx] = f2bf(tile[tx][ty + i]);
}

// ---------------------------------------------------------------------------
// GEMM: C = A[M][768] * Bt[N][768]^T, bf16. 128x384 block, BK=64, 8 waves
// 2x4 (wr=w>>2 owns 64 rows, wc=w&3 owns 96 cols), per-wave 4x6 frags of
// 16x16x32 MFMA. Fragment-order 1KB LDS blocks:
//   A: block = kc*8  + row16 (16 blocks, 16KB/tile)
//   B: block = kc*24 + row16 (48 blocks, 48KB/tile)
// Block holds rows row16*16+(lane&15), k = kc*32+(lane>>4)*8 at lane*16B ->
// glds16 staging and ds_read_b128 fragment reads both lane-sequential.
// Staging half h covers EXACTLY the blocks RD_*(.,h) reads:
//   A-h: row16 = ((w>>1)&1)*4 + h*2 + (w&1), kc = w>>2   (1 load/wave)
//   B-h: row16 = (w&3)*6 + h*3 + j (j=0..2), kc = w>>2   (3 loads/wave)
// MODE 0: write transposed bf16 Qt[bh][d][n]     (out0)
// MODE 1: cols<768 -> Kt[bh][d][n] (out0); cols>=768 -> Vb[m][768] (out1)
// MODE 2: fp32 + bias row-major (out0)
// ---------------------------------------------------------------------------

#define BAR __builtin_amdgcn_s_barrier()
#define VM(n) asm volatile("s_waitcnt vmcnt(" #n ")" ::: "memory")

#define ST_A(buf, tt, h) do { \
    const int r16a_ = ((w >> 1) & 1) * 4 + (h) * 2 + (w & 1); \
    const int kca_  = w >> 2; \
    glds16(gA + (size_t)(r16a_ * 16) * KD + (tt) * 64 + kca_ * 32, \
           &As[buf][(kca_ * 8 + r16a_) * 512]); \
} while (0)

#define ST_B(buf, tt, h) do { \
    const int kcb_ = w >> 2; \
    _Pragma("unroll") \
    for (int j_ = 0; j_ < 3; j_++) { \
        const int r16b_ = (w & 3) * 6 + (h) * 3 + j_; \
        glds16(gB + (size_t)(r16b_ * 16) * KD + (tt) * 64 + kcb_ * 32, \
               &Bs[buf][(kcb_ * 24 + r16b_) * 512]); \
    } \
} while (0)

#define RD_A(buf, mh) do { \
    _Pragma("unroll") \
    for (int i_ = 0; i_ < 2; i_++) \
    _Pragma("unroll") \
    for (int kk_ = 0; kk_ < 2; kk_++) \
        a[i_][kk_] = *(const bf16x8*)&As[buf][(kk_ * 8 + wr * 4 + (mh) * 2 + i_) * 512 + lane * 8]; \
} while (0)

#define RD_B(buf, nh) do { \
    _Pragma("unroll") \
    for (int j_ = 0; j_ < 3; j_++) \
    _Pragma("unroll") \
    for (int kk_ = 0; kk_ < 2; kk_++) \
        b[nh][j_][kk_] = *(const bf16x8*)&Bs[buf][(kk_ * 24 + wc * 6 + (nh) * 3 + j_) * 512 + lane * 8]; \
} while (0)

#define MM(mh, nh) do { \
    __builtin_amdgcn_s_setprio(1); \
    _Pragma("unroll") \
    for (int i_ = 0; i_ < 2; i_++) \
    _Pragma("unroll") \
    for (int j_ = 0; j_ < 3; j_++) \
    _Pragma("unroll") \
    for (int kk_ = 0; kk_ < 2; kk_++) \
        acc[(mh) * 2 + i_][(nh) * 3 + j_] = __builtin_amdgcn_mfma_f32_16x16x32_bf16( \
            a[i_][kk_], b[nh][j_][kk_], acc[(mh) * 2 + i_][(nh) * 3 + j_], 0, 0, 0); \
    __builtin_amdgcn_s_setprio(0); \
} while (0)

// one iteration = K-tiles t0 (buf0) and t0+1 (buf1), 8 phases.
#define KITER(t0v, LAST) do { \
    /* P1 */ RD_A(0, 0); RD_B(0, 0); ST_A(1, (t0v) + 1, 1); \
             BAR; MM(0, 0); VM(9); BAR; \
    /* P2 */ RD_B(0, 1); if (!(LAST)) ST_A(0, (t0v) + 2, 0); \
             BAR; MM(0, 1); if (LAST) { VM(8); } else { VM(9); } BAR; \
    /* P3 */ RD_A(0, 1); if (!(LAST)) ST_B(0, (t0v) + 2, 0); \
             BAR; MM(1, 0); BAR; \
    /* P4 */ if (!(LAST)) ST_B(0, (t0v) + 2, 1); \
             BAR; MM(1, 1); if (LAST) { VM(4); } else { VM(11); } BAR; \
    /* P5 */ RD_A(1, 0); RD_B(1, 0); if (!(LAST)) ST_A(0, (t0v) + 2, 1); \
             BAR; MM(0, 0); if (LAST) { VM(1); } else { VM(9); } BAR; \
    /* P6 */ RD_B(1, 1); if (!(LAST)) ST_A(1, (t0v) + 3, 0); \
             BAR; MM(0, 1); if (LAST) { VM(0); } else { VM(9); } BAR; \
    /* P7 */ RD_A(1, 1); if (!(LAST)) ST_B(1, (t0v) + 3, 0); \
             BAR; MM(1, 0); BAR; \
    /* P8 */ if (!(LAST)) { ST_B(1, (t0v) + 3, 1); } \
             BAR; MM(1, 1); if (!(LAST)) { VM(11); } BAR; \
} while (0)

template<int MODE>
__global__ __launch_bounds__(512, 2) void gemm_bt(
    const unsigned short* __restrict__ A, const unsigned short* __restrict__ Bt,
    const float* __restrict__ bias, void* __restrict__ out0, void* __restrict__ out1,
    int M, int N)
{
    __shared__ unsigned short As[2][8192];    // 2 x 16KB
    __shared__ unsigned short Bs[2][24576];   // 2 x 48KB

    const int Nt = gridDim.x, Mt = gridDim.y;
    const int lin = blockIdx.y * Nt + blockIdx.x;
    const int xcd = lin & 7, li = lin >> 3;
    const int band = Mt >> 3;
    const int mt = xcd * band + (li % band);
    const int nt = li / band;
    const int bm = mt * 128, bn = nt * 384;

    const int t = threadIdx.x, lane = t & 63, w = t >> 6;
    const int wr = w >> 2, wc = w & 3;            // 2 x 4 wave grid
    const int mf = lane & 15, quad = lane >> 4;

    const unsigned short* gA = A  + (size_t)(bm + (lane & 15)) * KD + (lane >> 4) * 8;
    const unsigned short* gB = Bt + (size_t)(bn + (lane & 15)) * KD + (lane >> 4) * 8;

    f32x4 acc[4][6] = {};
    bf16x8 a[2][2], b[2][3][2];

    // prologue: A0(0),B0(0),B1(0),A1(0) -> buf0; A0(1),B0(1),B1(1) -> buf1
    // = 15 loads; VM(11) forces oldest 4 = A0(0)+B0(0), needed at P1.
    ST_A(0, 0, 0); ST_B(0, 0, 0); ST_B(0, 0, 1); ST_A(0, 0, 1);
    ST_A(1, 1, 0); ST_B(1, 1, 0); ST_B(1, 1, 1);
    VM(11);
    BAR;

    // 12 K-tiles = 6 iterations
    #pragma unroll 1
    for (int it = 0; it < 5; ++it) { KITER(2 * it, false); }
    KITER(10, true);

    // C/D layout: col = lane&15, row = quad*4 + r
    if constexpr (MODE == 2) {
        float* C = (float*)out0;
        #pragma unroll
        for (int i = 0; i < 4; i++) {
            int row0 = bm + wr * 64 + i * 16 + quad * 4;
            #pragma unroll
            for (int j = 0; j < 6; j++) {
                int col = bn + wc * 96 + j * 16 + mf;
                float bv = bias[col];
                #pragma unroll
                for (int r = 0; r < 4; r++)
                    C[(size_t)(row0 + r) * N + col] = acc[i][j][r] + bv;
            }
        }
    } else {
        unsigned short* Tr = (unsigned short*)out0;   // Qt or Kt [bh][96][4096]
        unsigned short* Vb = (unsigned short*)out1;   // [16384][768]
        const bool kpart = (MODE == 0) || (bn < 768); // uniform (bn mult of 384)
        #pragma unroll
        for (int i = 0; i < 4; i++) {
            int row0 = bm + wr * 64 + i * 16 + quad * 4;  // global token index
            int bb = row0 >> 12, n = row0 & 4095;
            #pragma unroll
            for (int j = 0; j < 6; j++) {
                int c = bn + wc * 96 + j * 16 + mf;
                if (kpart) {
                    int h = (c * 683) >> 16;          // floor(c/96) for c<768
                    int d = c - h * 96;
                    size_t o = ((size_t)((bb * 8 + h) * 96 + d)) * 4096 + n;
                    ushort4 v4;
                    v4.x = f2bf(acc[i][j][0]); v4.y = f2bf(acc[i][j][1]);
                    v4.z = f2bf(acc[i][j][2]); v4.w = f2bf(acc[i][j][3]);
                    *(ushort4*)&Tr[o] = v4;
                } else {
                    int cv = c - 768;
                    #pragma unroll
                    for (int r = 0; r < 4; r++)
                        Vb[(size_t)(row0 + r) * 768 + cv] = f2bf(acc[i][j][r]);
                }
            }
        }
    }
}

#undef KITER
#undef MM
#undef RD_A
#undef RD_B
#undef ST_A
#undef ST_B
#undef VM
#undef BAR

// ---------------------------------------------------------------------------
// S-gram: Spart[bh][s][96][96] = sum over 512-n window of Qt[d][n]*Kt[e][n].
// ---------------------------------------------------------------------------
__global__ __launch_bounds__(256) void s_gemm(
    const unsigned short* __restrict__ Qt, const unsigned short* __restrict__ Kt,
    float* __restrict__ Spart, float* __restrict__ ssq)
{
    __shared__ unsigned short Qs[2][12 * 512];
    __shared__ unsigned short Ks[2][12 * 512];
    const int s = blockIdx.x, bh = blockIdx.y;
    const int t = threadIdx.x, lane = t & 63, w = t >> 6;
    const int m0 = (w >> 1) * 48, n0w = (w & 1) * 48;
    const int mf = lane & 15, quad = lane >> 4;
    const int srow = lane & 15, skc = (lane >> 4) * 8;
    const int nwin = s * 512;

    const unsigned short* Qg = Qt + (size_t)bh * 96 * 4096;
    const unsigned short* Kg = Kt + (size_t)bh * 96 * 4096;

    f32x4 acc[3][3] = {};
    float sq[3] = {0.f, 0.f, 0.f}, sk[3] = {0.f, 0.f, 0.f};

    #pragma unroll
    for (int c = 0; c < 3; c++) {
        int bi = w * 3 + c, kc = bi / 6, g = bi % 6;
        size_t go = (size_t)(g * 16 + srow) * 4096 + nwin + kc * 32 + skc;
        glds16(Qg + go, &Qs[0][bi * 512]);
        glds16(Kg + go, &Ks[0][bi * 512]);
    }

    for (int it = 0; it < 8; it++) {
        const int cur = it & 1;
        __syncthreads();
        if (it + 1 < 8) {
            const int nxt = cur ^ 1;
            const int nn = nwin + (it + 1) * 64;
            #pragma unroll
            for (int c = 0; c < 3; c++) {
                int bi = w * 3 + c, kc = bi / 6, g = bi % 6;
                size_t go = (size_t)(g * 16 + srow) * 4096 + nn + kc * 32 + skc;
                glds16(Qg + go, &Qs[nxt][bi * 512]);
                glds16(Kg + go, &Ks[nxt][bi * 512]);
            }
        }
        #pragma unroll
        for (int kk = 0; kk < 2; kk++) {
            bf16x8 a[3], b[3];
            #pragma unroll
            for (int i = 0; i < 3; i++)
                a[i] = *(const bf16x8*)&Qs[cur][(kk * 6 + (w >> 1) * 3 + i) * 512 + lane * 8];
            #pragma unroll
            for (int j = 0; j < 3; j++)
                b[j] = *(const bf16x8*)&Ks[cur][(kk * 6 + (w & 1) * 3 + j) * 512 + lane * 8];
            if ((w & 1) == 0) {
                #pragma unroll
                for (int i = 0; i < 3; i++) sq[i] += ssq8(a[i]);
            }
            if ((w >> 1) == 0) {
                #pragma unroll
                for (int j = 0; j < 3; j++) sk[j] += ssq8(b[j]);
            }
            #pragma unroll
            for (int i = 0; i < 3; i++)
                #pragma unroll
                for (int j = 0; j < 3; j++)
                    acc[i][j] = __builtin_amdgcn_mfma_f32_16x16x32_bf16(a[i], b[j], acc[i][j], 0, 0, 0);
        }
    }

    if ((w & 1) == 0) {
        #pragma unroll
        for (int i = 0; i < 3; i++) {
            float v = sq[i];
            v += __shfl_xor(v, 16, 64);
            v += __shfl_xor(v, 32, 64);
            if (lane < 16) atomicAdd(&ssq[bh * 96 + m0 + i * 16 + lane], v);
        }
    }
    if ((w >> 1) == 0) {
        #pragma unroll
        for (int j = 0; j < 3; j++) {
            float v = sk[j];
            v += __shfl_xor(v, 16, 64);
            v += __shfl_xor(v, 32, 64);
            if (lane < 16) atomicAdd(&ssq[3072 + bh * 96 + n0w + j * 16 + lane], v);
        }
    }

    float* outp = Spart + (size_t)(bh * 8 + s) * 9216;
    #pragma unroll
    for (int i = 0; i < 3; i++)
        #pragma unroll
        for (int j = 0; j < 3; j++) {
            int e  = n0w + j * 16 + mf;
            int d0 = m0 + i * 16 + quad * 4;
            #pragma unroll
            for (int r = 0; r < 4; r++)
                outp[(d0 + r) * 96 + e] = acc[i][j][r];
        }
}

// ---------------------------------------------------------------------------
// Softmax, wave-per-row: grid(24, 32bh) x 256 thr.
// ---------------------------------------------------------------------------
__global__ __launch_bounds__(256) void softmax_k(
    const float* __restrict__ Spart, const float* __restrict__ ssq,
    unsigned short* __restrict__ P)
{
    const int bh = blockIdx.y;
    const int d  = blockIdx.x * 4 + (threadIdx.x >> 6);
    const int lane = threadIdx.x & 63;

    const float sr = SCALE_ / fmaxf(sqrtf(ssq[bh * 96 + d]), 1e-12f);

    const float* Sp = Spart + (size_t)bh * 8 * 9216 + d * 96;
    float sa = 0.f, sb = 0.f;
    #pragma unroll
    for (int ch = 0; ch < 8; ch++) {
        sa += Sp[ch * 9216 + lane];
        if (lane < 32) sb += Sp[ch * 9216 + 64 + lane];
    }
    float ka = 1.0f / fmaxf(sqrtf(ssq[3072 + bh * 96 + lane]), 1e-12f);
    float va = sa * sr * ka;
    float vb = -1e30f;
    if (lane < 32) {
        float kb = 1.0f / fmaxf(sqrtf(ssq[3072 + bh * 96 + 64 + lane]), 1e-12f);
        vb = sb * sr * kb;
    }

    float m = fmaxf(va, vb);
    #pragma unroll
    for (int off = 32; off >= 1; off >>= 1)
        m = fmaxf(m, __shfl_xor(m, off, 64));

    float ea = __expf(va - m);
    float eb = (lane < 32) ? __expf(vb - m) : 0.f;
    float ssum = ea + eb;
    #pragma unroll
    for (int off = 32; off >= 1; off >>= 1)
        ssum += __shfl_xor(ssum, off, 64);

    float inv = 1.0f / ssum;
    unsigned short* Pr = P + (size_t)bh * 9216 + d * 96;
    Pr[lane] = f2bf(ea * inv);
    if (lane < 32) Pr[64 + lane] = f2bf(eb * inv);
}

// ---------------------------------------------------------------------------
// x[n][d] = sum_e V[n][e] * P[d][e] per (b,h). V from compact Vb[m][768].
// ---------------------------------------------------------------------------
__global__ __launch_bounds__(256) void pv_gemm(
    const unsigned short* __restrict__ Vb, const unsigned short* __restrict__ P,
    unsigned short* __restrict__ X)
{
    __shared__ unsigned short Ps[96][104];
    int ntile = blockIdx.x, bh = blockIdx.y;
    int b = bh >> 3, h = bh & 7;
    int t = threadIdx.x, lane = t & 63, w = t >> 6;

    const unsigned short* Pg = P + (size_t)bh * 9216;
    #pragma unroll
    for (int i = 0; i < 9; i++) {
        int idx4 = t + 256 * i;
        int row = idx4 / 24, c4 = (idx4 - row * 24) * 4;
        *(ushort4*)&Ps[row][c4] = *(const ushort4*)&Pg[row * 96 + c4];
    }
    __syncthreads();

    const unsigned short* Vbase = Vb + (size_t)b * 4096 * 768 + h * 96;
    int mf = lane & 15, k8 = (lane >> 4) * 8;
    f32x4 acc[2][6] = {};
    #pragma unroll
    for (int k = 0; k < 3; k++) {
        bf16x8 a[2], bb[6];
        #pragma unroll
        for (int i = 0; i < 2; i++) {
            int row = ntile * 128 + w * 32 + i * 16 + mf;
            a[i] = *(const bf16x8*)&Vbase[(size_t)row * 768 + k * 32 + k8];
        }
        #pragma unroll
        for (int j = 0; j < 6; j++)
            bb[j] = *(const bf16x8*)&Ps[j * 16 + mf][k * 32 + k8];
        #pragma unroll
        for (int i = 0; i < 2; i++)
            #pragma unroll
            for (int j = 0; j < 6; j++)
                acc[i][j] = __builtin_amdgcn_mfma_f32_16x16x32_bf16(a[i], bb[j], acc[i][j], 0, 0, 0);
    }
    #pragma unroll
    for (int i = 0; i < 2; i++)
        #pragma unroll
        for (int j = 0; j < 6; j++)
            #pragma unroll
            for (int r = 0; r < 4; r++) {
                int n_tok = ntile * 128 + w * 32 + i * 16 + (lane >> 4) * 4 + r;
                int c = h * 96 + j * 16 + mf;
                X[((size_t)b * 4096 + n_tok) * 768 + c] = f2bf(acc[i][j][r]);
            }
}

// ---------------------------------------------------------------------------
extern "C" void kernel_launch(void* const* d_in, const int* in_sizes, int n_in,
                              void* d_out, int out_size, void* d_ws, size_t ws_size,
                              hipStream_t stream)
{
    (void)in_sizes; (void)n_in; (void)out_size; (void)ws_size;
    const float* ctx   = (const float*)d_in[0];
    const float* dep   = (const float*)d_in[1];
    const float* Wq    = (const float*)d_in[2];
    const float* Wkv   = (const float*)d_in[3];
    const float* Wproj = (const float*)d_in[4];
    const float* bproj = (const float*)d_in[5];
    float* out = (float*)d_out;

    char* p = (char*)d_ws;
    auto carve = [&](size_t bytes) {
        char* r = p;
        p += (bytes + 255) & ~(size_t)255;
        return r;
    };
    unsigned short* WqT    = (unsigned short*)carve((size_t)768 * 768 * 2);
    unsigned short* WkvT   = (unsigned short*)carve((size_t)1536 * 768 * 2);
    unsigned short* WprojT = (unsigned short*)carve((size_t)768 * 768 * 2);
    unsigned short* Qt     = (unsigned short*)carve((size_t)32 * 96 * 4096 * 2);
    unsigned short* Kt     = (unsigned short*)carve((size_t)32 * 96 * 4096 * 2);
    unsigned short* Vb     = (unsigned short*)carve((size_t)16384 * 768 * 2);
    unsigned short* Xb     = (unsigned short*)carve((size_t)16384 * 768 * 2);
    float*          ssq    = (float*)carve((size_t)2 * 3072 * 4);
    float*          Spart  = (float*)carve((size_t)32 * 8 * 9216 * 4);
    unsigned short* Pb     = (unsigned short*)carve((size_t)32 * 9216 * 2);
    unsigned short* depB   = (unsigned short*)carve((size_t)16384 * 768 * 2);
    // ctx-bf16 aliases Xb: Q-gemm consumes it before pv_gemm writes Xb.
    unsigned short* ctxB   = Xb;

    hipMemsetAsync(ssq, 0, 2 * 3072 * 4, stream);

    f32_to_bf16_k<<<6144, 256, 0, stream>>>(ctx, ctxB);
    f32_to_bf16_k<<<6144, 256, 0, stream>>>(dep, depB);

    dim3 tb(32, 8);
    transpose_to_bf16<<<dim3(24, 24), tb, 0, stream>>>(Wq, WqT, 768, 768);
    transpose_to_bf16<<<dim3(48, 24), tb, 0, stream>>>(Wkv, WkvT, 768, 1536);
    transpose_to_bf16<<<dim3(24, 24), tb, 0, stream>>>(Wproj, WprojT, 768, 768);

    gemm_bt<0><<<dim3(2, 128), 512, 0, stream>>>(ctxB, WqT, nullptr, Qt, nullptr, 16384, 768);
    gemm_bt<1><<<dim3(4, 128), 512, 0, stream>>>(depB, WkvT, nullptr, Kt, Vb, 16384, 1536);

    s_gemm<<<dim3(8, 32), 256, 0, stream>>>(Qt, Kt, Spart, ssq);
    softmax_k<<<dim3(24, 32), 256, 0, stream>>>(Spart, ssq, Pb);
    pv_gemm<<<dim3(32, 32), 256, 0, stream>>>(Vb, Pb, Xb);
    gemm_bt<2><<<dim3(2, 128), 512, 0, stream>>>(Xb, WprojT, bproj, out, nullptr, 16384, 768);
}